// Round 5
// baseline (345.757 us; speedup 1.0000x reference)
//
#include <hip/hip_runtime.h>

// Anchor generation: out[(a,y,x), 0..3] = {cx-w2[a], cy-h2[a], cx+w2[a], cy+h2[a]}
// cx=(x+0.5)*8, cy=(y+0.5)*8 ; fh=fw=1024, 9 anchor shapes (3 scales x 3 ratios).
// Pure streaming-write kernel, ~151 MB fp32 output. Inputs are shape-only.
//
// Launch exactly 2^20 threads (4096 blocks x 256). Grid stride == one anchor
// plane (2^20 float4s), so per-thread (x,y,cx,cy) is computed ONCE and the
// anchor-shape loop a=0..8 is fully unrolled with w2/h2 as literal constants.
//
// NOTE: __builtin_nontemporal_store requires a clang vector type, not HIP's
// float4 class — use ext_vector_type(4).

typedef float vf4 __attribute__((ext_vector_type(4)));

__global__ __launch_bounds__(256) void anchor_gen_kernel(vf4* __restrict__ out) {
    const unsigned t = blockIdx.x * 256u + threadIdx.x;   // [0, 2^20)
    const float x = (float)(t & 1023u);
    const float y = (float)(t >> 10);
    const float cx = fmaf(x, 8.0f, 4.0f);   // (x+0.5)*8
    const float cy = fmaf(y, 8.0f, 4.0f);

    // w2[a] = scale*sqrt(ratio)/2, h2[a] = scale/sqrt(ratio)/2
    // scales (8,16,32) x ratios (0.5,1,2), a = s*3 + r.
    constexpr float W2[9] = {
        2.82842712474619f, 4.0f,  5.65685424949238f,
        5.65685424949238f, 8.0f,  11.3137084989848f,
        11.3137084989848f, 16.0f, 22.6274169979695f
    };
    constexpr float H2[9] = {
        5.65685424949238f,  4.0f,  2.82842712474619f,
        11.3137084989848f,  8.0f,  5.65685424949238f,
        22.6274169979695f,  16.0f, 11.3137084989848f
    };

#pragma unroll
    for (int a = 0; a < 9; ++a) {
        vf4 v;
        v.x = cx - W2[a];
        v.y = cy - H2[a];
        v.z = cx + W2[a];
        v.w = cy + H2[a];
        __builtin_nontemporal_store(v, &out[((unsigned)a << 20) | t]);
    }
}

extern "C" void kernel_launch(void* const* d_in, const int* in_sizes, int n_in,
                              void* d_out, int out_size, void* d_ws, size_t ws_size,
                              hipStream_t stream) {
    (void)d_in; (void)in_sizes; (void)n_in; (void)d_ws; (void)ws_size; (void)out_size;
    anchor_gen_kernel<<<4096, 256, 0, stream>>>((vf4*)d_out);
}

// Round 6
// 338.855 us; speedup vs baseline: 1.0204x; 1.0204x over previous
//
#include <hip/hip_runtime.h>

// Anchor generation: out[(a,y,x), 0..3] = {cx-w2[a], cy-h2[a], cx+w2[a], cy+h2[a]}
// cx=(x+0.5)*8, cy=(y+0.5)*8 ; fh=fw=1024, 9 anchor shapes (3 scales x 3 ratios).
// Pure streaming-write kernel, ~151 MB fp32 output. Inputs are shape-only.
//
// Launch exactly 2^20 threads (4096 blocks x 256). Grid stride == one anchor
// plane (2^20 float4s), so per-thread (x,y,cx,cy) is computed ONCE and the
// anchor-shape loop a=0..8 is fully unrolled with w2/h2 as literal constants.
//
// Round-5 lesson: nontemporal stores HURT (+12us) — the 151 MB output fits
// the 256 MB Infinity Cache, so plain cached stores are absorbed by L3;
// nt bypasses it and pays full HBM write cost. Use plain stores.

typedef float vf4 __attribute__((ext_vector_type(4)));

__global__ __launch_bounds__(256) void anchor_gen_kernel(vf4* __restrict__ out) {
    const unsigned t = blockIdx.x * 256u + threadIdx.x;   // [0, 2^20)
    const float x = (float)(t & 1023u);
    const float y = (float)(t >> 10);
    const float cx = fmaf(x, 8.0f, 4.0f);   // (x+0.5)*8
    const float cy = fmaf(y, 8.0f, 4.0f);

    // w2[a] = scale*sqrt(ratio)/2, h2[a] = scale/sqrt(ratio)/2
    // scales (8,16,32) x ratios (0.5,1,2), a = s*3 + r.
    constexpr float W2[9] = {
        2.82842712474619f, 4.0f,  5.65685424949238f,
        5.65685424949238f, 8.0f,  11.3137084989848f,
        11.3137084989848f, 16.0f, 22.6274169979695f
    };
    constexpr float H2[9] = {
        5.65685424949238f,  4.0f,  2.82842712474619f,
        11.3137084989848f,  8.0f,  5.65685424949238f,
        22.6274169979695f,  16.0f, 11.3137084989848f
    };

#pragma unroll
    for (int a = 0; a < 9; ++a) {
        vf4 v;
        v.x = cx - W2[a];
        v.y = cy - H2[a];
        v.z = cx + W2[a];
        v.w = cy + H2[a];
        out[((unsigned)a << 20) | t] = v;
    }
}

extern "C" void kernel_launch(void* const* d_in, const int* in_sizes, int n_in,
                              void* d_out, int out_size, void* d_ws, size_t ws_size,
                              hipStream_t stream) {
    (void)d_in; (void)in_sizes; (void)n_in; (void)d_ws; (void)ws_size; (void)out_size;
    anchor_gen_kernel<<<4096, 256, 0, stream>>>((vf4*)d_out);
}